// Round 10
// baseline (282.411 us; speedup 1.0000x reference)
//
#include <hip/hip_runtime.h>
#include <hip/hip_bf16.h>

#define BB 4096
#define DD 64
#define HH 512

typedef __hip_bfloat16 bf16;
typedef _Float16 f16;
typedef __attribute__((ext_vector_type(8))) short bf16x8;
typedef __attribute__((ext_vector_type(8))) _Float16 f16x8;
typedef __attribute__((ext_vector_type(4))) float f32x4;

__device__ __forceinline__ float bf2f(bf16 x) { return __bfloat162float(x); }
__device__ __forceinline__ float u16tof(unsigned short u) {
  union { unsigned int i; float f; } v; v.i = ((unsigned int)u) << 16; return v.f;
}
#define BC8(p) __builtin_bit_cast(bf16x8, *(const uint4*)(p))
#define BCH8(p) __builtin_bit_cast(f16x8, *(const uint4*)(p))

// async global->LDS, 16B per lane. LDS dest = wave-uniform base + lane*16.
__device__ __forceinline__ void gl16(const void* g, void* l) {
  __builtin_amdgcn_global_load_lds((__attribute__((address_space(1))) void*)g,
                                   (__attribute__((address_space(3))) void*)l,
                                   16, 0, 0);
}

// ws: Xbf | Ybf (B*H bf16) | W1sw (f16 swz) | W2fr (f16 frag) | W3T (f32 T) |
//     W2fb | V2fb (bf16 frag, HxH) | W1fb | V1fb (bf16 frag, 512x64) |
//     W3bf | V3bf (bf16 natural) | Jpart (2 x B x 64 f32)   ~11.3 MB

// ---------------------------------------------------------------------------
// Fragment layout (generic, unit = 8 elems = 16B): for B-operand matrix
// M[n][k] (n = out-col, k = contraction), unit uid = (ks*N + n)*4 + q holds
// M[n][ks*32 + q*8 .. +8]. A lane (c,q) of the fragment for n-tile n0 reads
// 16B at ((ks*N + n0 + c)*4 + q)*16 -- 1KB contiguous per fragment.
// cvt blocks:
//  [0,128)   W2fr  f16 frags of W2 (k4's B)
//  [128,144) W1sw  f16 XOR-swizzled W1T (k4's LDS A)
//  [144,208) W3bf/V3bf natural bf16
//  [208,240) W3T[h][o] = W3[o][h] f32
//  [240,368) W2fb  bf16 frags of W2 (fwd L2 B)
//  [368,496) V2fb  bf16 frags of V2
//  [496,512) W1fb  bf16 frags of W1 (fwd L1 B, K=64)
//  [512,528) V1fb  bf16 frags of V1
// ---------------------------------------------------------------------------
__global__ __launch_bounds__(256) void cvt_weights(
    const float* __restrict__ W2, const float* __restrict__ V2,
    const float* __restrict__ W1, const float* __restrict__ V1,
    const float* __restrict__ W3, const float* __restrict__ V3,
    f16* __restrict__ W2fr, f16* __restrict__ W1sw, float* __restrict__ W3T,
    bf16* __restrict__ W2fb, bf16* __restrict__ V2fb,
    bf16* __restrict__ W1fb, bf16* __restrict__ V1fb,
    bf16* __restrict__ W3bf, bf16* __restrict__ V3bf) {
  int blk = blockIdx.x, t = threadIdx.x;
  if (blk < 128) {
    int uid = blk * 256 + t;                  // 0..32767
    int col = (uid >> 2) & 511;
    int ks = uid >> 11, q = uid & 3;
    const float* src = W2 + (size_t)col * HH + ks * 32 + q * 8;
    float4 a = *(const float4*)src;
    float4 b = *(const float4*)(src + 4);
    f16 o[8] = {(f16)a.x, (f16)a.y, (f16)a.z, (f16)a.w,
                (f16)b.x, (f16)b.y, (f16)b.z, (f16)b.w};
    *(uint4*)(W2fr + (size_t)uid * 8) = *(uint4*)o;
  } else if (blk < 144) {
    int uid = (blk - 128) * 256 + t;          // 0..4095
    int kc = uid >> 9, rem = uid & 511;
    int dl = rem >> 3, u = rem & 7;
    f16 o[8];
#pragma unroll
    for (int e = 0; e < 8; ++e)
      o[e] = (f16)W1[(size_t)(kc * 64 + u * 8 + e) * DD + dl];
    *(uint4*)(W1sw + (size_t)((kc * 64 + dl) * 8 + (u ^ (dl & 7))) * 8) = *(uint4*)o;
  } else if (blk < 208) {
    int which = (blk - 144) >> 5;
    int local = (blk - 144) & 31;
    const float* src = (which == 0) ? W3 : V3;
    bf16* dst = (which == 0) ? W3bf : V3bf;
    int i = (local * 256 + t) * 4;
    float4 v = *(const float4*)(src + i);
    bf16 o[4] = {__float2bfloat16(v.x), __float2bfloat16(v.y),
                 __float2bfloat16(v.z), __float2bfloat16(v.w)};
    *(uint2*)(dst + i) = *(uint2*)o;
  } else if (blk < 240) {
    int e = ((blk - 208) * 256 + t) * 4;      // 0..32767
    int h = e >> 6, o0 = e & 63;
    float o[4];
#pragma unroll
    for (int j = 0; j < 4; ++j) o[j] = W3[(size_t)(o0 + j) * HH + h];
    *(float4*)(W3T + (size_t)h * 64 + o0) = *(float4*)o;
  } else if (blk < 496) {
    int uid = (blk - 240) * 256 + t;          // 0..65535 over W2fb|V2fb
    const float* S = (uid < 32768) ? W2 : V2;
    bf16* D = (uid < 32768) ? W2fb : V2fb;
    uid &= 32767;
    int col = (uid >> 2) & 511;
    int ks = uid >> 11, q = uid & 3;
    const float* src = S + (size_t)col * HH + ks * 32 + q * 8;
    float4 a = *(const float4*)src;
    float4 b = *(const float4*)(src + 4);
    bf16 o[8] = {__float2bfloat16(a.x), __float2bfloat16(a.y),
                 __float2bfloat16(a.z), __float2bfloat16(a.w),
                 __float2bfloat16(b.x), __float2bfloat16(b.y),
                 __float2bfloat16(b.z), __float2bfloat16(b.w)};
    *(uint4*)(D + (size_t)uid * 8) = *(uint4*)o;
  } else {
    int uid = (blk - 496) * 256 + t;          // 0..8191 over W1fb|V1fb
    const float* S = (uid < 4096) ? W1 : V1;
    bf16* D = (uid < 4096) ? W1fb : V1fb;
    uid &= 4095;
    int col = (uid >> 2) & 511;
    int ks = uid >> 11, q = uid & 3;          // ks in {0,1}
    const float* src = S + (size_t)col * DD + ks * 32 + q * 8;
    float4 a = *(const float4*)src;
    float4 b = *(const float4*)(src + 4);
    bf16 o[8] = {__float2bfloat16(a.x), __float2bfloat16(a.y),
                 __float2bfloat16(a.z), __float2bfloat16(a.w),
                 __float2bfloat16(b.x), __float2bfloat16(b.y),
                 __float2bfloat16(b.z), __float2bfloat16(b.w)};
    *(uint4*)(D + (size_t)uid * 8) = *(uint4*)o;
  }
}

// ---------------------------------------------------------------------------
// fwd v3 (R8 verbatim): all weights streamed from L2 as register fragments;
// 4 barriers/block; grid (256,2), 512 thr, LDS 68 KB.
// ---------------------------------------------------------------------------
__global__ __launch_bounds__(512, 4) void fwd(
    const float* __restrict__ states,
    const bf16* __restrict__ W1fb, const float* __restrict__ b1,
    const bf16* __restrict__ W2fb, const float* __restrict__ b2,
    const bf16* __restrict__ W3bf, const float* __restrict__ b3,
    const bf16* __restrict__ V1fb, const float* __restrict__ c1,
    const bf16* __restrict__ V2fb, const float* __restrict__ c2,
    const bf16* __restrict__ V3bf, const float* __restrict__ c3,
    bf16* __restrict__ Xbf, bf16* __restrict__ Ybf, float* __restrict__ out) {
  __shared__ __align__(16) bf16 mus[16 * 72];      //  2.3 KB
  __shared__ __align__(16) bf16 Xres[16 * 520];    // 16.3 KB
  __shared__ __align__(16) bf16 Ych[16 * 520];     // 16.3 KB
  __shared__ __align__(16) float red[8 * 16 * 66]; // 33.8 KB (padded planes)
  const int bt = blockIdx.x * 16;
  const int path = blockIdx.y;
  const bf16* Wa = path ? V1fb : W1fb;
  const float* ba = path ? c1 : b1;
  const bf16* Wb = path ? V2fb : W2fb;
  const float* bbv = path ? c2 : b2;
  const bf16* Wc = path ? V3bf : W3bf;
  const float* bcv = path ? c3 : b3;
  const int t = threadIdx.x;
  const int lane = t & 63;
  const int w = t >> 6;                      // 0..7, owns cols w*64..+64
  const int c = lane & 15, q = lane >> 4;

  if (t < 128) {
    int row = t >> 3, cg = (t & 7) * 8;
    bf16 o[8];
#pragma unroll
    for (int j = 0; j < 8; j += 4) {
      float4 v = *(const float4*)(states + (size_t)(bt + row) * 128 + cg + j);
      o[j] = __float2bfloat16(v.x); o[j + 1] = __float2bfloat16(v.y);
      o[j + 2] = __float2bfloat16(v.z); o[j + 3] = __float2bfloat16(v.w);
    }
    *(uint4*)(mus + row * 72 + cg) = *(const uint4*)o;
  }
  __syncthreads();

  // ---- L1: X = tanh(mu @ Wa^T + ba); B-frags streamed from L2 ----
  f32x4 acc1[4] = {};
#pragma unroll
  for (int s = 0; s < 2; ++s) {
    bf16x8 af = BC8(mus + c * 72 + s * 32 + q * 8);
#pragma unroll
    for (int nt = 0; nt < 4; ++nt) {
      bf16x8 bfr = BC8(Wa + ((size_t)(s * 512 + w * 64 + nt * 16 + c) * 4 + q) * 8);
      acc1[nt] = __builtin_amdgcn_mfma_f32_16x16x32_bf16(af, bfr, acc1[nt], 0, 0, 0);
    }
  }
#pragma unroll
  for (int nt = 0; nt < 4; ++nt) {
    int col = w * 64 + nt * 16 + c;
    float bias = ba[col];
#pragma unroll
    for (int r = 0; r < 4; ++r) {
      int row = q * 4 + r;
      float x = tanhf(acc1[nt][r] + bias);
      Xres[row * 520 + col] = __float2bfloat16(x);
      if (!path) Xbf[(size_t)(bt + row) * HH + col] = __float2bfloat16(x);
    }
  }
  __syncthreads();

  // ---- L2: Y = tanh(X @ Wb^T + bbv); zero barriers in the K-loop ----
  f32x4 acc2[4] = {};
  for (int kc = 0; kc < 8; ++kc) {
#pragma unroll
    for (int s = 0; s < 2; ++s) {
      int ks = kc * 2 + s;
      bf16x8 af = BC8(Xres + c * 520 + kc * 64 + s * 32 + q * 8);
#pragma unroll
      for (int nt = 0; nt < 4; ++nt) {
        bf16x8 bfr = BC8(Wb + ((size_t)(ks * 512 + w * 64 + nt * 16 + c) * 4 + q) * 8);
        acc2[nt] = __builtin_amdgcn_mfma_f32_16x16x32_bf16(af, bfr, acc2[nt], 0, 0, 0);
      }
    }
  }
#pragma unroll
  for (int nt = 0; nt < 4; ++nt) {
    int col = w * 64 + nt * 16 + c;
    float bias = bbv[col];
#pragma unroll
    for (int r = 0; r < 4; ++r) {
      int row = q * 4 + r;
      float y = tanhf(acc2[nt][r] + bias);
      Ych[row * 520 + col] = __float2bfloat16(y);
      if (!path) Ybf[(size_t)(bt + row) * HH + col] = __float2bfloat16(y);
    }
  }
  __syncthreads();

  // ---- L3: per-wave partial over its own h-slice; Wc read natural ----
  f32x4 acc3[4] = {};
#pragma unroll
  for (int s3 = 0; s3 < 2; ++s3) {
    bf16x8 af3 = BC8(Ych + c * 520 + w * 64 + s3 * 32 + q * 8);
#pragma unroll
    for (int nt = 0; nt < 4; ++nt) {
      bf16x8 bf3 = BC8(Wc + (size_t)(nt * 16 + c) * HH + w * 64 + s3 * 32 + q * 8);
      acc3[nt] = __builtin_amdgcn_mfma_f32_16x16x32_bf16(af3, bf3, acc3[nt], 0, 0, 0);
    }
  }
#pragma unroll
  for (int nt = 0; nt < 4; ++nt)
#pragma unroll
    for (int r = 0; r < 4; ++r)
      red[w * 1056 + (q * 4 + r) * 66 + nt * 16 + c] = acc3[nt][r];
  __syncthreads();

  // ---- reduce 8 wave-planes; bias + (softplus | identity); write out ----
#pragma unroll
  for (int oidx = t; oidx < 1024; oidx += 512) {
    int row = oidx >> 6, o = oidx & 63;
    float v = bcv[o];
#pragma unroll
    for (int wp = 0; wp < 8; ++wp) v += red[wp * 1056 + row * 66 + o];
    if (path) {
      v = fmaxf(v, 0.0f) + log1pf(expf(-fabsf(v)));
      out[(size_t)(bt + row) * 128 + 64 + o] = v;
    } else {
      out[(size_t)(bt + row) * 128 + o] = v;
    }
  }
}

// ---------------------------------------------------------------------------
// k4 v17 (R8 verbatim -- best measured; reg-exact at 256/wave):
// B streamed from L2 (W2fr frag-ordered, double-buffered one K-step ahead);
// LDS holds full W1T (staged once) + d1 + d2. Zero barriers in the K-loop.
// 512 thr, 8 waves 2Mx4N, wave tile 128x64. grid (1024, 2).
// ---------------------------------------------------------------------------
#define LDSW1 0
#define LDSD1 65536
#define LDSD2 73728
#define LDSRED 77824

__global__ __launch_bounds__(512, 2) void k4_gemm(
    const bf16* __restrict__ Xbf, const bf16* __restrict__ Ybf,
    const f16* __restrict__ W1sw, const f16* __restrict__ W2fr,
    const float* __restrict__ W3T, float* __restrict__ Jpart) {
  __shared__ __align__(16) char lds[81920];
  const int bt = blockIdx.x;                 // 256-row group: rows bt*256+m
  const int h0 = blockIdx.y * 256;
  const int t = threadIdx.x;
  const int lane = t & 63;
  const int w = t >> 6;
  const int c = lane & 15, q = lane >> 4;
  const int wr = w >> 2, wc = w & 3;         // 2M x 4N wave grid
  const int b0 = bt * 4;

  // ---- prologue: stage full W1T (64 KB) once; d1, d2 ----
#pragma unroll
  for (int i = 0; i < 8; ++i)
    gl16((const char*)W1sw + (t + i * 512) * 16,
         (char*)lds + LDSW1 + (t + i * 512) * 16);
  {
    int e = t * 4, j = e >> 9, k = e & 511;
    ushort4 xv = *(const ushort4*)((const unsigned short*)Xbf +
                                   (size_t)(b0 + j) * HH + k);
    f16 o[4];
    float x;
    x = u16tof(xv.x); o[0] = (f16)(1.f - x * x);
    x = u16tof(xv.y); o[1] = (f16)(1.f - x * x);
    x = u16tof(xv.z); o[2] = (f16)(1.f - x * x);
    x = u16tof(xv.w); o[3] = (f16)(1.f - x * x);
    *(uint2*)(lds + LDSD1 + e * 2) = *(uint2*)o;
  }
  {
    int e = t * 2, j = e >> 8, n = e & 255;
    ushort2 yv = *(const ushort2*)((const unsigned short*)Ybf +
                                   (size_t)(b0 + j) * HH + h0 + n);
    float y0 = u16tof(yv.x), y1 = u16tof(yv.y);
    float2 d2v = {1.f - y0 * y0, 1.f - y1 * y1};
    *(float2*)(lds + LDSD2 + e * 4) = d2v;
  }
  __syncthreads();   // drains gl_lds (vmcnt0) + d1/d2 visible

  const int cj = c & 7;
  const int j16_0 = ((0 + q) ^ cj) * 16;     // s=0 swizzled unit offset
  const int j16_1 = ((4 + q) ^ cj) * 16;     // s=1
  const int arow = c * 128;
  const char* d1b = (const char*)lds + LDSD1 + wr * 2048 + q * 16;

  // B fragment global addressing: frag(kc,s,nt) is 1 KB contiguous.
  const char* gB = (const char*)W2fr + (size_t)(h0 + wc * 64) * 64 +
                   (c * 64 + q * 16);
#define BLD(kc_, s_, nt_) \
  BCH8(gB + ((kc_) * 2 + (s_)) * 32768 + (nt_) * 1024)

  // double-buffered B fragments: parity = kc&1 (static after full unroll)
  f16x8 bb0[2][4], bb1[2][4];
#pragma unroll
  for (int nt = 0; nt < 4; ++nt) bb0[0][nt] = BLD(0, 0, nt);
#pragma unroll
  for (int nt = 0; nt < 4; ++nt) bb1[0][nt] = BLD(0, 1, nt);

  f32x4 acc[8][4] = {};

#pragma unroll
  for (int kc = 0; kc < 8; ++kc) {
    const int cur = kc & 1, nxt = cur ^ 1;
    // issue next K-step's B loads first (max latency cover)
    if (kc < 7) {
#pragma unroll
      for (int nt = 0; nt < 4; ++nt) bb0[nxt][nt] = BLD(kc + 1, 0, nt);
#pragma unroll
      for (int nt = 0; nt < 4; ++nt) bb1[nxt][nt] = BLD(kc + 1, 1, nt);
    }
    // A fragments + d1 for this K-step (read-only LDS, no sync needed)
    const char* Ab = (const char*)lds + LDSW1 + kc * 8192;
    f16x8 a0[4], a1[4];
#pragma unroll
    for (int i = 0; i < 4; ++i) a0[i] = BCH8(Ab + arow + i * 2048 + j16_0);
#pragma unroll
    for (int i = 0; i < 4; ++i) a1[i] = BCH8(Ab + arow + i * 2048 + j16_1);
    f16x8 d00 = BCH8(d1b + kc * 128);
    f16x8 d10 = BCH8(d1b + 1024 + kc * 128);
    f16x8 d01 = BCH8(d1b + 64 + kc * 128);
    f16x8 d11 = BCH8(d1b + 1024 + 64 + kc * 128);

    f16x8 av;
#pragma unroll
    for (int mt = 0; mt < 4; ++mt) {
      av = a0[mt] * d00;
#pragma unroll
      for (int nt = 0; nt < 4; ++nt)
        acc[mt][nt] = __builtin_amdgcn_mfma_f32_16x16x32_f16(
            av, bb0[cur][nt], acc[mt][nt], 0, 0, 0);
    }
#pragma unroll
    for (int mt = 0; mt < 4; ++mt) {
      av = a0[mt] * d10;
#pragma unroll
      for (int nt = 0; nt < 4; ++nt)
        acc[mt + 4][nt] = __builtin_amdgcn_mfma_f32_16x16x32_f16(
            av, bb0[cur][nt], acc[mt + 4][nt], 0, 0, 0);
    }
#pragma unroll
    for (int mt = 0; mt < 4; ++mt) {
      av = a1[mt] * d01;
#pragma unroll
      for (int nt = 0; nt < 4; ++nt)
        acc[mt][nt] = __builtin_amdgcn_mfma_f32_16x16x32_f16(
            av, bb1[cur][nt], acc[mt][nt], 0, 0, 0);
    }
#pragma unroll
    for (int mt = 0; mt < 4; ++mt) {
      av = a1[mt] * d11;
#pragma unroll
      for (int nt = 0; nt < 4; ++nt)
        acc[mt + 4][nt] = __builtin_amdgcn_mfma_f32_16x16x32_f16(
            av, bb1[cur][nt], acc[mt + 4][nt], 0, 0, 0);
    }
    __builtin_amdgcn_sched_barrier(0);   // pin kc-region boundary
  }
  __syncthreads();   // all waves done reading W1T/d1 before overlay

  // ---- epilogue: w3s[col*72+dl] = W3[dl][h0+col], staged from W3T via
  // float4 loads+stores (balanced banks), overlaid on dead W1T region ----
#pragma unroll
  for (int i = 0; i < 8; ++i) {
    int e = (t + i * 512) * 4;
    int col = e >> 6, dl0 = e & 63;
    float4 v = *(const float4*)(W3T + (size_t)(h0 + col) * 64 + dl0);
    *(float4*)(lds + (col * 72 + dl0) * 4) = v;
  }
  __syncthreads();

  float d2r[2][4];
#pragma unroll
  for (int bh = 0; bh < 2; ++bh)
#pragma unroll
    for (int nt = 0; nt < 4; ++nt)
      d2r[bh][nt] = *(const float*)(
          lds + LDSD2 + ((wr * 2 + bh) * 256 + wc * 64 + nt * 16 + c) * 4);

  float vsum[8][4] = {};
#pragma unroll
  for (int mt4 = 0; mt4 < 4; ++mt4)
#pragma unroll
    for (int nt = 0; nt < 4; ++nt) {
      f32x4 w3v = *(const f32x4*)(
          lds + ((wc * 64 + nt * 16 + c) * 72 + mt4 * 16 + q * 4) * 4);
#pragma unroll
      for (int bh = 0; bh < 2; ++bh) {
        const int mt = bh * 4 + mt4;
        float sc = d2r[bh][nt];
#pragma unroll
        for (int r = 0; r < 4; ++r)
          vsum[mt][r] += acc[mt][nt][r] * w3v[r] * sc;
      }
    }

#pragma unroll
  for (int mt = 0; mt < 8; ++mt)
#pragma unroll
    for (int r = 0; r < 4; ++r) {
      float v = vsum[mt][r];
      v += __shfl_xor(v, 1);
      v += __shfl_xor(v, 2);
      v += __shfl_xor(v, 4);
      v += __shfl_xor(v, 8);
      if (c == 0)
        *(float*)(lds + LDSRED +
                  (wc * 256 + wr * 128 + mt * 16 + q * 4 + r) * 4) = v;
    }
  __syncthreads();
  if (t < 256) {
    float J = *(const float*)(lds + LDSRED + t * 4) +
              *(const float*)(lds + LDSRED + (256 + t) * 4) +
              *(const float*)(lds + LDSRED + (512 + t) * 4) +
              *(const float*)(lds + LDSRED + (768 + t) * 4);
    Jpart[(size_t)blockIdx.y * (BB * 64) + (size_t)bt * 256 + t] = J;
  }
}

// ---------------------------------------------------------------------------
// combine: out[b,64+d] = 2*(sum of 2 Jpart planes)*sigma + out (Qd stash)
// ---------------------------------------------------------------------------
__global__ __launch_bounds__(256) void combine(
    const float* __restrict__ Jpart, const float* __restrict__ states,
    float* __restrict__ out) {
  int idx = blockIdx.x * 256 + threadIdx.x;
  int b = idx >> 6, d = idx & 63;
  const int plane = BB * 64;
  float J = Jpart[idx] + Jpart[plane + idx];
  float sig = states[(size_t)b * 128 + 64 + d];
  float qd = out[(size_t)b * 128 + 64 + d];
  out[(size_t)b * 128 + 64 + d] = 2.0f * J * sig + qd;
}

extern "C" void kernel_launch(void* const* d_in, const int* in_sizes, int n_in,
                              void* d_out, int out_size, void* d_ws, size_t ws_size,
                              hipStream_t stream) {
  // inputs: 0:t 1:states 2:W1 3:b1 4:W2 5:b2 6:W3 7:b3 8:V1 9:c1 10:V2 11:c2 12:V3 13:c3
  const float* states = (const float*)d_in[1];
  const float* W1 = (const float*)d_in[2];
  const float* b1 = (const float*)d_in[3];
  const float* W2 = (const float*)d_in[4];
  const float* b2 = (const float*)d_in[5];
  const float* W3 = (const float*)d_in[6];
  const float* b3 = (const float*)d_in[7];
  const float* V1 = (const float*)d_in[8];
  const float* c1 = (const float*)d_in[9];
  const float* V2 = (const float*)d_in[10];
  const float* c2 = (const float*)d_in[11];
  const float* V3 = (const float*)d_in[12];
  const float* c3 = (const float*)d_in[13];
  float* out = (float*)d_out;

  bf16* Xbf = (bf16*)d_ws;                         // B*H  (4 MB)
  bf16* Ybf = Xbf + (size_t)BB * HH;               // B*H  (4 MB)
  f16* W1sw = (f16*)(Ybf + (size_t)BB * HH);       // 64x512 f16 swizzled
  f16* W2fr = W1sw + (size_t)DD * HH;              // H*H f16 frag-ordered
  float* W3T = (float*)(W2fr + (size_t)HH * HH);   // 512x64 f32 transposed
  bf16* W2fb = (bf16*)(W3T + (size_t)HH * DD);     // H*H bf16 frag-ordered
  bf16* V2fb = W2fb + (size_t)HH * HH;             // H*H bf16 frag-ordered
  bf16* W1fb = V2fb + (size_t)HH * HH;             // 512x64 bf16 frag (K=64)
  bf16* V1fb = W1fb + (size_t)HH * DD;             // 512x64 bf16 frag
  bf16* W3bf = V1fb + (size_t)HH * DD;             // 64x512 bf16 natural
  bf16* V3bf = W3bf + (size_t)DD * HH;             // 64x512 bf16 natural
  float* Jpart = (float*)(V3bf + (size_t)DD * HH); // 2*B*64 f32 (2 MB)

  cvt_weights<<<dim3(528), 256, 0, stream>>>(W2, V2, W1, V1, W3, V3,
                                             W2fr, W1sw, W3T,
                                             W2fb, V2fb, W1fb, V1fb,
                                             W3bf, V3bf);
  fwd<<<dim3(256, 2), 512, 0, stream>>>(states, W1fb, b1, W2fb, b2, W3bf, b3,
                                        V1fb, c1, V2fb, c2, V3bf, c3,
                                        Xbf, Ybf, out);
  k4_gemm<<<dim3(1024, 2), 512, 0, stream>>>(Xbf, Ybf, W1sw, W2fr, W3T, Jpart);
  combine<<<dim3(1024), 256, 0, stream>>>(Jpart, states, out);
}

// Round 11
// 258.491 us; speedup vs baseline: 1.0925x; 1.0925x over previous
//
#include <hip/hip_runtime.h>
#include <hip/hip_bf16.h>

#define BB 4096
#define DD 64
#define HH 512

typedef __hip_bfloat16 bf16;
typedef _Float16 f16;
typedef __attribute__((ext_vector_type(8))) short bf16x8;
typedef __attribute__((ext_vector_type(8))) _Float16 f16x8;
typedef __attribute__((ext_vector_type(4))) float f32x4;

__device__ __forceinline__ float bf2f(bf16 x) { return __bfloat162float(x); }
__device__ __forceinline__ float u16tof(unsigned short u) {
  union { unsigned int i; float f; } v; v.i = ((unsigned int)u) << 16; return v.f;
}
#define BC8(p) __builtin_bit_cast(bf16x8, *(const uint4*)(p))
#define BCH8(p) __builtin_bit_cast(f16x8, *(const uint4*)(p))

// async global->LDS, 16B per lane. LDS dest = wave-uniform base + lane*16.
__device__ __forceinline__ void gl16(const void* g, void* l) {
  __builtin_amdgcn_global_load_lds((__attribute__((address_space(1))) void*)g,
                                   (__attribute__((address_space(3))) void*)l,
                                   16, 0, 0);
}

// ws: Xbf | Ybf (B*H bf16) | W1sw (f16 swz) | W2fr (f16 frag) | W3T (f32 T) |
//     W2fb | V2fb (bf16 frag, HxH) | W1fb | V1fb (bf16 frag, 512x64) |
//     W3bf | V3bf (bf16 natural) | Jpart (2 x B x 64 f32)   ~11.3 MB
//
// FINAL CONFIG (session converged): fwd = register-streamed L2 weights (R8);
// k4 = v17 (B from L2 double-buffered, W1T-in-LDS once, zero-barrier K-loop);
// separate combine (fused-atomic variant measured worse, R9). Structural
// ceiling: k4 is latency-bound at 2 waves/SIMD (128 AGPR acc + ~124 VGPR =
// ~252/wave on the unified file); all occupancy escapes measured worse
// (R5: L2 amplification; R7: persistence locality loss; R1-R3: phase
// pipelining null at this geometry).

// ---------------------------------------------------------------------------
// Fragment layout (generic, unit = 8 elems = 16B): for B-operand matrix
// M[n][k] (n = out-col, k = contraction), unit uid = (ks*N + n)*4 + q holds
// M[n][ks*32 + q*8 .. +8]. A lane (c,q) of the fragment for n-tile n0 reads
// 16B at ((ks*N + n0 + c)*4 + q)*16 -- 1KB contiguous per fragment.
// ---------------------------------------------------------------------------
__global__ __launch_bounds__(256) void cvt_weights(
    const float* __restrict__ W2, const float* __restrict__ V2,
    const float* __restrict__ W1, const float* __restrict__ V1,
    const float* __restrict__ W3, const float* __restrict__ V3,
    f16* __restrict__ W2fr, f16* __restrict__ W1sw, float* __restrict__ W3T,
    bf16* __restrict__ W2fb, bf16* __restrict__ V2fb,
    bf16* __restrict__ W1fb, bf16* __restrict__ V1fb,
    bf16* __restrict__ W3bf, bf16* __restrict__ V3bf) {
  int blk = blockIdx.x, t = threadIdx.x;
  if (blk < 128) {
    int uid = blk * 256 + t;                  // 0..32767
    int col = (uid >> 2) & 511;
    int ks = uid >> 11, q = uid & 3;
    const float* src = W2 + (size_t)col * HH + ks * 32 + q * 8;
    float4 a = *(const float4*)src;
    float4 b = *(const float4*)(src + 4);
    f16 o[8] = {(f16)a.x, (f16)a.y, (f16)a.z, (f16)a.w,
                (f16)b.x, (f16)b.y, (f16)b.z, (f16)b.w};
    *(uint4*)(W2fr + (size_t)uid * 8) = *(uint4*)o;
  } else if (blk < 144) {
    int uid = (blk - 128) * 256 + t;          // 0..4095
    int kc = uid >> 9, rem = uid & 511;
    int dl = rem >> 3, u = rem & 7;
    f16 o[8];
#pragma unroll
    for (int e = 0; e < 8; ++e)
      o[e] = (f16)W1[(size_t)(kc * 64 + u * 8 + e) * DD + dl];
    *(uint4*)(W1sw + (size_t)((kc * 64 + dl) * 8 + (u ^ (dl & 7))) * 8) = *(uint4*)o;
  } else if (blk < 208) {
    int which = (blk - 144) >> 5;
    int local = (blk - 144) & 31;
    const float* src = (which == 0) ? W3 : V3;
    bf16* dst = (which == 0) ? W3bf : V3bf;
    int i = (local * 256 + t) * 4;
    float4 v = *(const float4*)(src + i);
    bf16 o[4] = {__float2bfloat16(v.x), __float2bfloat16(v.y),
                 __float2bfloat16(v.z), __float2bfloat16(v.w)};
    *(uint2*)(dst + i) = *(uint2*)o;
  } else if (blk < 240) {
    int e = ((blk - 208) * 256 + t) * 4;      // 0..32767
    int h = e >> 6, o0 = e & 63;
    float o[4];
#pragma unroll
    for (int j = 0; j < 4; ++j) o[j] = W3[(size_t)(o0 + j) * HH + h];
    *(float4*)(W3T + (size_t)h * 64 + o0) = *(float4*)o;
  } else if (blk < 496) {
    int uid = (blk - 240) * 256 + t;          // 0..65535 over W2fb|V2fb
    const float* S = (uid < 32768) ? W2 : V2;
    bf16* D = (uid < 32768) ? W2fb : V2fb;
    uid &= 32767;
    int col = (uid >> 2) & 511;
    int ks = uid >> 11, q = uid & 3;
    const float* src = S + (size_t)col * HH + ks * 32 + q * 8;
    float4 a = *(const float4*)src;
    float4 b = *(const float4*)(src + 4);
    bf16 o[8] = {__float2bfloat16(a.x), __float2bfloat16(a.y),
                 __float2bfloat16(a.z), __float2bfloat16(a.w),
                 __float2bfloat16(b.x), __float2bfloat16(b.y),
                 __float2bfloat16(b.z), __float2bfloat16(b.w)};
    *(uint4*)(D + (size_t)uid * 8) = *(uint4*)o;
  } else {
    int uid = (blk - 496) * 256 + t;          // 0..8191 over W1fb|V1fb
    const float* S = (uid < 4096) ? W1 : V1;
    bf16* D = (uid < 4096) ? W1fb : V1fb;
    uid &= 4095;
    int col = (uid >> 2) & 511;
    int ks = uid >> 11, q = uid & 3;          // ks in {0,1}
    const float* src = S + (size_t)col * DD + ks * 32 + q * 8;
    float4 a = *(const float4*)src;
    float4 b = *(const float4*)(src + 4);
    bf16 o[8] = {__float2bfloat16(a.x), __float2bfloat16(a.y),
                 __float2bfloat16(a.z), __float2bfloat16(a.w),
                 __float2bfloat16(b.x), __float2bfloat16(b.y),
                 __float2bfloat16(b.z), __float2bfloat16(b.w)};
    *(uint4*)(D + (size_t)uid * 8) = *(uint4*)o;
  }
}

// ---------------------------------------------------------------------------
// fwd (R8 verbatim): all weights streamed from L2 as register fragments;
// 4 barriers/block; grid (256,2), 512 thr, LDS 68 KB.
// ---------------------------------------------------------------------------
__global__ __launch_bounds__(512, 4) void fwd(
    const float* __restrict__ states,
    const bf16* __restrict__ W1fb, const float* __restrict__ b1,
    const bf16* __restrict__ W2fb, const float* __restrict__ b2,
    const bf16* __restrict__ W3bf, const float* __restrict__ b3,
    const bf16* __restrict__ V1fb, const float* __restrict__ c1,
    const bf16* __restrict__ V2fb, const float* __restrict__ c2,
    const bf16* __restrict__ V3bf, const float* __restrict__ c3,
    bf16* __restrict__ Xbf, bf16* __restrict__ Ybf, float* __restrict__ out) {
  __shared__ __align__(16) bf16 mus[16 * 72];      //  2.3 KB
  __shared__ __align__(16) bf16 Xres[16 * 520];    // 16.3 KB
  __shared__ __align__(16) bf16 Ych[16 * 520];     // 16.3 KB
  __shared__ __align__(16) float red[8 * 16 * 66]; // 33.8 KB (padded planes)
  const int bt = blockIdx.x * 16;
  const int path = blockIdx.y;
  const bf16* Wa = path ? V1fb : W1fb;
  const float* ba = path ? c1 : b1;
  const bf16* Wb = path ? V2fb : W2fb;
  const float* bbv = path ? c2 : b2;
  const bf16* Wc = path ? V3bf : W3bf;
  const float* bcv = path ? c3 : b3;
  const int t = threadIdx.x;
  const int lane = t & 63;
  const int w = t >> 6;                      // 0..7, owns cols w*64..+64
  const int c = lane & 15, q = lane >> 4;

  if (t < 128) {
    int row = t >> 3, cg = (t & 7) * 8;
    bf16 o[8];
#pragma unroll
    for (int j = 0; j < 8; j += 4) {
      float4 v = *(const float4*)(states + (size_t)(bt + row) * 128 + cg + j);
      o[j] = __float2bfloat16(v.x); o[j + 1] = __float2bfloat16(v.y);
      o[j + 2] = __float2bfloat16(v.z); o[j + 3] = __float2bfloat16(v.w);
    }
    *(uint4*)(mus + row * 72 + cg) = *(const uint4*)o;
  }
  __syncthreads();

  // ---- L1: X = tanh(mu @ Wa^T + ba); B-frags streamed from L2 ----
  f32x4 acc1[4] = {};
#pragma unroll
  for (int s = 0; s < 2; ++s) {
    bf16x8 af = BC8(mus + c * 72 + s * 32 + q * 8);
#pragma unroll
    for (int nt = 0; nt < 4; ++nt) {
      bf16x8 bfr = BC8(Wa + ((size_t)(s * 512 + w * 64 + nt * 16 + c) * 4 + q) * 8);
      acc1[nt] = __builtin_amdgcn_mfma_f32_16x16x32_bf16(af, bfr, acc1[nt], 0, 0, 0);
    }
  }
#pragma unroll
  for (int nt = 0; nt < 4; ++nt) {
    int col = w * 64 + nt * 16 + c;
    float bias = ba[col];
#pragma unroll
    for (int r = 0; r < 4; ++r) {
      int row = q * 4 + r;
      float x = tanhf(acc1[nt][r] + bias);
      Xres[row * 520 + col] = __float2bfloat16(x);
      if (!path) Xbf[(size_t)(bt + row) * HH + col] = __float2bfloat16(x);
    }
  }
  __syncthreads();

  // ---- L2: Y = tanh(X @ Wb^T + bbv); zero barriers in the K-loop ----
  f32x4 acc2[4] = {};
  for (int kc = 0; kc < 8; ++kc) {
#pragma unroll
    for (int s = 0; s < 2; ++s) {
      int ks = kc * 2 + s;
      bf16x8 af = BC8(Xres + c * 520 + kc * 64 + s * 32 + q * 8);
#pragma unroll
      for (int nt = 0; nt < 4; ++nt) {
        bf16x8 bfr = BC8(Wb + ((size_t)(ks * 512 + w * 64 + nt * 16 + c) * 4 + q) * 8);
        acc2[nt] = __builtin_amdgcn_mfma_f32_16x16x32_bf16(af, bfr, acc2[nt], 0, 0, 0);
      }
    }
  }
#pragma unroll
  for (int nt = 0; nt < 4; ++nt) {
    int col = w * 64 + nt * 16 + c;
    float bias = bbv[col];
#pragma unroll
    for (int r = 0; r < 4; ++r) {
      int row = q * 4 + r;
      float y = tanhf(acc2[nt][r] + bias);
      Ych[row * 520 + col] = __float2bfloat16(y);
      if (!path) Ybf[(size_t)(bt + row) * HH + col] = __float2bfloat16(y);
    }
  }
  __syncthreads();

  // ---- L3: per-wave partial over its own h-slice; Wc read natural ----
  f32x4 acc3[4] = {};
#pragma unroll
  for (int s3 = 0; s3 < 2; ++s3) {
    bf16x8 af3 = BC8(Ych + c * 520 + w * 64 + s3 * 32 + q * 8);
#pragma unroll
    for (int nt = 0; nt < 4; ++nt) {
      bf16x8 bf3 = BC8(Wc + (size_t)(nt * 16 + c) * HH + w * 64 + s3 * 32 + q * 8);
      acc3[nt] = __builtin_amdgcn_mfma_f32_16x16x32_bf16(af3, bf3, acc3[nt], 0, 0, 0);
    }
  }
#pragma unroll
  for (int nt = 0; nt < 4; ++nt)
#pragma unroll
    for (int r = 0; r < 4; ++r)
      red[w * 1056 + (q * 4 + r) * 66 + nt * 16 + c] = acc3[nt][r];
  __syncthreads();

  // ---- reduce 8 wave-planes; bias + (softplus | identity); write out ----
#pragma unroll
  for (int oidx = t; oidx < 1024; oidx += 512) {
    int row = oidx >> 6, o = oidx & 63;
    float v = bcv[o];
#pragma unroll
    for (int wp = 0; wp < 8; ++wp) v += red[wp * 1056 + row * 66 + o];
    if (path) {
      v = fmaxf(v, 0.0f) + log1pf(expf(-fabsf(v)));
      out[(size_t)(bt + row) * 128 + 64 + o] = v;
    } else {
      out[(size_t)(bt + row) * 128 + o] = v;
    }
  }
}

// ---------------------------------------------------------------------------
// k4 v17 (best measured; reg-exact at ~252/wave -> 2 waves/SIMD):
// B streamed from L2 (W2fr frag-ordered, double-buffered one K-step ahead);
// LDS holds full W1T (staged once) + d1 + d2. Zero barriers in the K-loop.
// 512 thr, 8 waves 2Mx4N, wave tile 128x64. grid (1024, 2).
// ---------------------------------------------------------------------------
#define LDSW1 0
#define LDSD1 65536
#define LDSD2 73728
#define LDSRED 77824

__global__ __launch_bounds__(512, 2) void k4_gemm(
    const bf16* __restrict__ Xbf, const bf16* __restrict__ Ybf,
    const f16* __restrict__ W1sw, const f16* __restrict__ W2fr,
    const float* __restrict__ W3T, float* __restrict__ Jpart) {
  __shared__ __align__(16) char lds[81920];
  const int bt = blockIdx.x;                 // 256-row group: rows bt*256+m
  const int h0 = blockIdx.y * 256;
  const int t = threadIdx.x;
  const int lane = t & 63;
  const int w = t >> 6;
  const int c = lane & 15, q = lane >> 4;
  const int wr = w >> 2, wc = w & 3;         // 2M x 4N wave grid
  const int b0 = bt * 4;

  // ---- prologue: stage full W1T (64 KB) once; d1, d2 ----
#pragma unroll
  for (int i = 0; i < 8; ++i)
    gl16((const char*)W1sw + (t + i * 512) * 16,
         (char*)lds + LDSW1 + (t + i * 512) * 16);
  {
    int e = t * 4, j = e >> 9, k = e & 511;
    ushort4 xv = *(const ushort4*)((const unsigned short*)Xbf +
                                   (size_t)(b0 + j) * HH + k);
    f16 o[4];
    float x;
    x = u16tof(xv.x); o[0] = (f16)(1.f - x * x);
    x = u16tof(xv.y); o[1] = (f16)(1.f - x * x);
    x = u16tof(xv.z); o[2] = (f16)(1.f - x * x);
    x = u16tof(xv.w); o[3] = (f16)(1.f - x * x);
    *(uint2*)(lds + LDSD1 + e * 2) = *(uint2*)o;
  }
  {
    int e = t * 2, j = e >> 8, n = e & 255;
    ushort2 yv = *(const ushort2*)((const unsigned short*)Ybf +
                                   (size_t)(b0 + j) * HH + h0 + n);
    float y0 = u16tof(yv.x), y1 = u16tof(yv.y);
    float2 d2v = {1.f - y0 * y0, 1.f - y1 * y1};
    *(float2*)(lds + LDSD2 + e * 4) = d2v;
  }
  __syncthreads();   // drains gl_lds (vmcnt0) + d1/d2 visible

  const int cj = c & 7;
  const int j16_0 = ((0 + q) ^ cj) * 16;     // s=0 swizzled unit offset
  const int j16_1 = ((4 + q) ^ cj) * 16;     // s=1
  const int arow = c * 128;
  const char* d1b = (const char*)lds + LDSD1 + wr * 2048 + q * 16;

  // B fragment global addressing: frag(kc,s,nt) is 1 KB contiguous.
  const char* gB = (const char*)W2fr + (size_t)(h0 + wc * 64) * 64 +
                   (c * 64 + q * 16);
#define BLD(kc_, s_, nt_) \
  BCH8(gB + ((kc_) * 2 + (s_)) * 32768 + (nt_) * 1024)

  // double-buffered B fragments: parity = kc&1 (static after full unroll)
  f16x8 bb0[2][4], bb1[2][4];
#pragma unroll
  for (int nt = 0; nt < 4; ++nt) bb0[0][nt] = BLD(0, 0, nt);
#pragma unroll
  for (int nt = 0; nt < 4; ++nt) bb1[0][nt] = BLD(0, 1, nt);

  f32x4 acc[8][4] = {};

#pragma unroll
  for (int kc = 0; kc < 8; ++kc) {
    const int cur = kc & 1, nxt = cur ^ 1;
    // issue next K-step's B loads first (max latency cover)
    if (kc < 7) {
#pragma unroll
      for (int nt = 0; nt < 4; ++nt) bb0[nxt][nt] = BLD(kc + 1, 0, nt);
#pragma unroll
      for (int nt = 0; nt < 4; ++nt) bb1[nxt][nt] = BLD(kc + 1, 1, nt);
    }
    // A fragments + d1 for this K-step (read-only LDS, no sync needed)
    const char* Ab = (const char*)lds + LDSW1 + kc * 8192;
    f16x8 a0[4], a1[4];
#pragma unroll
    for (int i = 0; i < 4; ++i) a0[i] = BCH8(Ab + arow + i * 2048 + j16_0);
#pragma unroll
    for (int i = 0; i < 4; ++i) a1[i] = BCH8(Ab + arow + i * 2048 + j16_1);
    f16x8 d00 = BCH8(d1b + kc * 128);
    f16x8 d10 = BCH8(d1b + 1024 + kc * 128);
    f16x8 d01 = BCH8(d1b + 64 + kc * 128);
    f16x8 d11 = BCH8(d1b + 1024 + 64 + kc * 128);

    f16x8 av;
#pragma unroll
    for (int mt = 0; mt < 4; ++mt) {
      av = a0[mt] * d00;
#pragma unroll
      for (int nt = 0; nt < 4; ++nt)
        acc[mt][nt] = __builtin_amdgcn_mfma_f32_16x16x32_f16(
            av, bb0[cur][nt], acc[mt][nt], 0, 0, 0);
    }
#pragma unroll
    for (int mt = 0; mt < 4; ++mt) {
      av = a0[mt] * d10;
#pragma unroll
      for (int nt = 0; nt < 4; ++nt)
        acc[mt + 4][nt] = __builtin_amdgcn_mfma_f32_16x16x32_f16(
            av, bb0[cur][nt], acc[mt + 4][nt], 0, 0, 0);
    }
#pragma unroll
    for (int mt = 0; mt < 4; ++mt) {
      av = a1[mt] * d01;
#pragma unroll
      for (int nt = 0; nt < 4; ++nt)
        acc[mt][nt] = __builtin_amdgcn_mfma_f32_16x16x32_f16(
            av, bb1[cur][nt], acc[mt][nt], 0, 0, 0);
    }
#pragma unroll
    for (int mt = 0; mt < 4; ++mt) {
      av = a1[mt] * d11;
#pragma unroll
      for (int nt = 0; nt < 4; ++nt)
        acc[mt + 4][nt] = __builtin_amdgcn_mfma_f32_16x16x32_f16(
            av, bb1[cur][nt], acc[mt + 4][nt], 0, 0, 0);
    }
    __builtin_amdgcn_sched_barrier(0);   // pin kc-region boundary
  }
  __syncthreads();   // all waves done reading W1T/d1 before overlay

  // ---- epilogue: w3s[col*72+dl] = W3[dl][h0+col], staged from W3T via
  // float4 loads+stores (balanced banks), overlaid on dead W1T region ----
#pragma unroll
  for (int i = 0; i < 8; ++i) {
    int e = (t + i * 512) * 4;
    int col = e >> 6, dl0 = e & 63;
    float4 v = *(const float4*)(W3T + (size_t)(h0 + col) * 64 + dl0);
    *(float4*)(lds + (col * 72 + dl0) * 4) = v;
  }
  __syncthreads();

  float d2r[2][4];
#pragma unroll
  for (int bh = 0; bh < 2; ++bh)
#pragma unroll
    for (int nt = 0; nt < 4; ++nt)
      d2r[bh][nt] = *(const float*)(
          lds + LDSD2 + ((wr * 2 + bh) * 256 + wc * 64 + nt * 16 + c) * 4);

  float vsum[8][4] = {};
#pragma unroll
  for (int mt4 = 0; mt4 < 4; ++mt4)
#pragma unroll
    for (int nt = 0; nt < 4; ++nt) {
      f32x4 w3v = *(const f32x4*)(
          lds + ((wc * 64 + nt * 16 + c) * 72 + mt4 * 16 + q * 4) * 4);
#pragma unroll
      for (int bh = 0; bh < 2; ++bh) {
        const int mt = bh * 4 + mt4;
        float sc = d2r[bh][nt];
#pragma unroll
        for (int r = 0; r < 4; ++r)
          vsum[mt][r] += acc[mt][nt][r] * w3v[r] * sc;
      }
    }

#pragma unroll
  for (int mt = 0; mt < 8; ++mt)
#pragma unroll
    for (int r = 0; r < 4; ++r) {
      float v = vsum[mt][r];
      v += __shfl_xor(v, 1);
      v += __shfl_xor(v, 2);
      v += __shfl_xor(v, 4);
      v += __shfl_xor(v, 8);
      if (c == 0)
        *(float*)(lds + LDSRED +
                  (wc * 256 + wr * 128 + mt * 16 + q * 4 + r) * 4) = v;
    }
  __syncthreads();
  if (t < 256) {
    float J = *(const float*)(lds + LDSRED + t * 4) +
              *(const float*)(lds + LDSRED + (256 + t) * 4) +
              *(const float*)(lds + LDSRED + (512 + t) * 4) +
              *(const float*)(lds + LDSRED + (768 + t) * 4);
    Jpart[(size_t)blockIdx.y * (BB * 64) + (size_t)bt * 256 + t] = J;
  }
}

// ---------------------------------------------------------------------------
// combine: out[b,64+d] = 2*(sum of 2 Jpart planes)*sigma + out (Qd stash)
// ---------------------------------------------------------------------------
__global__ __launch_bounds__(256) void combine(
    const float* __restrict__ Jpart, const float* __restrict__ states,
    float* __restrict__ out) {
  int idx = blockIdx.x * 256 + threadIdx.x;
  int b = idx >> 6, d = idx & 63;
  const int plane = BB * 64;
  float J = Jpart[idx] + Jpart[plane + idx];
  float sig = states[(size_t)b * 128 + 64 + d];
  float qd = out[(size_t)b * 128 + 64 + d];
  out[(size_t)b * 128 + 64 + d] = 2.0f * J * sig + qd;
}

extern "C" void kernel_launch(void* const* d_in, const int* in_sizes, int n_in,
                              void* d_out, int out_size, void* d_ws, size_t ws_size,
                              hipStream_t stream) {
  // inputs: 0:t 1:states 2:W1 3:b1 4:W2 5:b2 6:W3 7:b3 8:V1 9:c1 10:V2 11:c2 12:V3 13:c3
  const float* states = (const float*)d_in[1];
  const float* W1 = (const float*)d_in[2];
  const float* b1 = (const float*)d_in[3];
  const float* W2 = (const float*)d_in[4];
  const float* b2 = (const float*)d_in[5];
  const float* W3 = (const float*)d_in[6];
  const float* b3 = (const float*)d_in[7];
  const float* V1 = (const float*)d_in[8];
  const float* c1 = (const float*)d_in[9];
  const float* V2 = (const float*)d_in[10];
  const float* c2 = (const float*)d_in[11];
  const float* V3 = (const float*)d_in[12];
  const float* c3 = (const float*)d_in[13];
  float* out = (float*)d_out;

  bf16* Xbf = (bf16*)d_ws;                         // B*H  (4 MB)
  bf16* Ybf = Xbf + (size_t)BB * HH;               // B*H  (4 MB)
  f16* W1sw = (f16*)(Ybf + (size_t)BB * HH);       // 64x512 f16 swizzled
  f16* W2fr = W1sw + (size_t)DD * HH;              // H*H f16 frag-ordered
  float* W3T = (float*)(W2fr + (size_t)HH * HH);   // 512x64 f32 transposed
  bf16* W2fb = (bf16*)(W3T + (size_t)HH * DD);     // H*H bf16 frag-ordered
  bf16* V2fb = W2fb + (size_t)HH * HH;             // H*H bf16 frag-ordered
  bf16* W1fb = V2fb + (size_t)HH * HH;             // 512x64 bf16 frag (K=64)
  bf16* V1fb = W1fb + (size_t)HH * DD;             // 512x64 bf16 frag
  bf16* W3bf = V1fb + (size_t)HH * DD;             // 64x512 bf16 natural
  bf16* V3bf = W3bf + (size_t)DD * HH;             // 64x512 bf16 natural
  float* Jpart = (float*)(V3bf + (size_t)DD * HH); // 2*B*64 f32 (2 MB)

  cvt_weights<<<dim3(528), 256, 0, stream>>>(W2, V2, W1, V1, W3, V3,
                                             W2fr, W1sw, W3T,
                                             W2fb, V2fb, W1fb, V1fb,
                                             W3bf, V3bf);
  fwd<<<dim3(256, 2), 512, 0, stream>>>(states, W1fb, b1, W2fb, b2, W3bf, b3,
                                        V1fb, c1, V2fb, c2, V3bf, c3,
                                        Xbf, Ybf, out);
  k4_gemm<<<dim3(1024, 2), 512, 0, stream>>>(Xbf, Ybf, W1sw, W2fr, W3T, Jpart);
  combine<<<dim3(1024), 256, 0, stream>>>(Jpart, states, out);
}